// Round 7
// baseline (353.359 us; speedup 1.0000x reference)
//
#include <hip/hip_runtime.h>
#include <math.h>

#define NROWS 4096
#define EDIM  1024
#define VOCAB 50257
#define KNOISE 50
#define KTOT  51
#define NPAIRS (NROWS * KTOT)        // 208,896
#define NORM_TERM 9.0f
#define NSLOTS 256
#define NB    197                    // ceil(VOCAB/256)
#define WR    4                      // vocab rows per wave in main
#define IN_SCALE     32.0f           // input pre-scale for e4m3
#define INV_IN_SCALE (1.0f / 32.0f)

typedef float floatx2 __attribute__((ext_vector_type(2)));
typedef float nfloat4 __attribute__((ext_vector_type(4)));   // native, OK for nontemporal

// ---- workspace layout (bytes) ----------------------------------------------
#define WS_PARTIAL 0            //  256 f32
#define WS_HIST    1024         //  VOCAB i32 (zeroed)
#define WS_CURSOR  202752       //  VOCAB i32 (written by scan_final)
#define WS_BASE    404480       //  VOCAB i32
#define WS_BSUM    606208       //  NB i32
#define WS_BOFF    607232       //  NB i32
#define WS_PAYLOAD 608256       //  NPAIRS i32
#define WS_IN8     1444864      //  NROWS*EDIM fp8 (4,194,304 B)
#define WS_NEED    (WS_IN8 + (size_t)NROWS * EDIM)

// ---- k1: convert input f32 -> fp8 e4m3 (scaled) + pair histogram -----------
__global__ __launch_bounds__(256) void convert_input_hist(
    const float* __restrict__ input, uint4* __restrict__ in8,
    const int* __restrict__ target, const int* __restrict__ noise_samples,
    int* __restrict__ hist)
{
    const int i = blockIdx.x * 256 + threadIdx.x;
    const float4* p = (const float4*)input + 4 * (size_t)i;
    float4 a0 = p[0], a1 = p[1], a2 = p[2], a3 = p[3];
    uint4 o;
    int d;
    d = 0;
    d = __builtin_amdgcn_cvt_pk_fp8_f32(a0.x * IN_SCALE, a0.y * IN_SCALE, d, false);
    d = __builtin_amdgcn_cvt_pk_fp8_f32(a0.z * IN_SCALE, a0.w * IN_SCALE, d, true);
    o.x = (unsigned int)d;
    d = 0;
    d = __builtin_amdgcn_cvt_pk_fp8_f32(a1.x * IN_SCALE, a1.y * IN_SCALE, d, false);
    d = __builtin_amdgcn_cvt_pk_fp8_f32(a1.z * IN_SCALE, a1.w * IN_SCALE, d, true);
    o.y = (unsigned int)d;
    d = 0;
    d = __builtin_amdgcn_cvt_pk_fp8_f32(a2.x * IN_SCALE, a2.y * IN_SCALE, d, false);
    d = __builtin_amdgcn_cvt_pk_fp8_f32(a2.z * IN_SCALE, a2.w * IN_SCALE, d, true);
    o.z = (unsigned int)d;
    d = 0;
    d = __builtin_amdgcn_cvt_pk_fp8_f32(a3.x * IN_SCALE, a3.y * IN_SCALE, d, false);
    d = __builtin_amdgcn_cvt_pk_fp8_f32(a3.z * IN_SCALE, a3.w * IN_SCALE, d, true);
    o.w = (unsigned int)d;
    in8[i] = o;

    if (i < NPAIRS) {
        const int n = i / KTOT;
        const int k = i - n * KTOT;
        const int v = (k == 0) ? target[n] : noise_samples[n * KNOISE + k - 1];
        atomicAdd(&hist[v], 1);
    }
}

// ---- k2: per-256-chunk sums of hist ----------------------------------------
__global__ __launch_bounds__(256) void scan_blocksum(
    const int* __restrict__ hist, int* __restrict__ bsum)
{
    const int b = blockIdx.x, t = threadIdx.x, i = b * 256 + t;
    int x = (i < VOCAB) ? hist[i] : 0;
#pragma unroll
    for (int off = 32; off > 0; off >>= 1) x += __shfl_xor(x, off, 64);
    __shared__ int s[4];
    if ((t & 63) == 0) s[t >> 6] = x;
    __syncthreads();
    if (t == 0) bsum[b] = s[0] + s[1] + s[2] + s[3];
}

// ---- k3: exclusive scan of the NB chunk sums (1 block) ---------------------
__global__ __launch_bounds__(256) void scan_offsets(
    const int* __restrict__ bsum, int* __restrict__ boff)
{
    const int t = threadIdx.x;
    __shared__ int s[256];
    const int x = (t < NB) ? bsum[t] : 0;
    s[t] = x;
    __syncthreads();
#pragma unroll
    for (int off = 1; off < 256; off <<= 1) {
        const int v = (t >= off) ? s[t - off] : 0;
        __syncthreads();
        s[t] += v;
        __syncthreads();
    }
    if (t < NB) boff[t] = s[t] - x;    // exclusive
}

// ---- k4: final exclusive scan -> base[], cursor[] --------------------------
__global__ __launch_bounds__(256) void scan_final(
    const int* __restrict__ hist, const int* __restrict__ boff,
    int* __restrict__ base, int* __restrict__ cursor)
{
    const int b = blockIdx.x, t = threadIdx.x, i = b * 256 + t;
    const int x = (i < VOCAB) ? hist[i] : 0;
    __shared__ int s[256];
    s[t] = x;
    __syncthreads();
#pragma unroll
    for (int off = 1; off < 256; off <<= 1) {
        const int v = (t >= off) ? s[t - off] : 0;
        __syncthreads();
        s[t] += v;
        __syncthreads();
    }
    if (i < VOCAB) {
        const int e = boff[b] + s[t] - x;
        base[i] = e;
        cursor[i] = e;
    }
}

// ---- k5: scatter pair payloads into CSR ------------------------------------
__global__ __launch_bounds__(256) void scatter_pairs(
    const int* __restrict__ target, const int* __restrict__ noise_samples,
    int* __restrict__ cursor, int* __restrict__ payload)
{
    const int m = blockIdx.x * 256 + threadIdx.x;    // grid 816 -> exactly NPAIRS
    const int n = m / KTOT;
    const int k = m - n * KTOT;
    const int v = (k == 0) ? target[n] : noise_samples[n * KNOISE + k - 1];
    const int slot = atomicAdd(&cursor[v], 1);
    payload[slot] = (n << 6) | k;
}

// ---- k6: inverted main -----------------------------------------------------
// One wave per WR=4 consecutive vocab rows. Per row v: stream the 4KB f32
// weight row ONCE into registers (nontemporal; lane holds elems [16L,16L+16)),
// then for each referencing pair (n,k): gather input row n as fp8 (one
// dwordx4/lane from the 4.2MB L2-resident table), dot, term. Per-wave atomic.
__global__ __launch_bounds__(256) void nce_main_inv(
    const uint4* __restrict__ in8,
    const float* __restrict__ weight,
    const float* __restrict__ bias,
    const float* __restrict__ noise,
    const int*   __restrict__ base,
    const int*   __restrict__ hist,
    const int*   __restrict__ payload,
    float*       __restrict__ partial)
{
    const int tid  = threadIdx.x;
    const int wave = tid >> 6;
    const int lane = tid & 63;
    const int gw   = blockIdx.x * 4 + wave;

    float acc = 0.0f;

    for (int j = 0; j < WR; ++j) {
        const int v = gw * WR + j;
        if (v >= VOCAB) break;                          // wave-uniform

        const nfloat4* wr4 = (const nfloat4*)(weight + (size_t)v * EDIM);
        nfloat4 wf[4];
#pragma unroll
        for (int p = 0; p < 4; ++p)
            wf[p] = __builtin_nontemporal_load(&wr4[4 * lane + p]);

        const int   r0  = __builtin_amdgcn_readfirstlane(base[v]);
        const int   cnt = __builtin_amdgcn_readfirstlane(hist[v]);
        const float bz  = bias[v];
        const float cz  = (float)KNOISE * noise[v];

        int i = 0;
        for (; i + 4 <= cnt; i += 4) {
            int pl[4];
#pragma unroll
            for (int q = 0; q < 4; ++q)
                pl[q] = __builtin_amdgcn_readfirstlane(payload[r0 + i + q]);
            uint4 c[4];
#pragma unroll
            for (int q = 0; q < 4; ++q)
                c[q] = in8[(size_t)(pl[q] >> 6) * 64 + lane];
            float dot[4] = {0.f, 0.f, 0.f, 0.f};
#pragma unroll
            for (int q = 0; q < 4; ++q) {
                const unsigned int wd[4] = { c[q].x, c[q].y, c[q].z, c[q].w };
#pragma unroll
                for (int d = 0; d < 4; ++d) {
                    const floatx2 f0 = __builtin_amdgcn_cvt_pk_f32_fp8((int)wd[d], false);
                    const floatx2 f1 = __builtin_amdgcn_cvt_pk_f32_fp8((int)wd[d], true);
                    dot[q] = fmaf(wf[d].x, f0.x, dot[q]);
                    dot[q] = fmaf(wf[d].y, f0.y, dot[q]);
                    dot[q] = fmaf(wf[d].z, f1.x, dot[q]);
                    dot[q] = fmaf(wf[d].w, f1.y, dot[q]);
                }
            }
#pragma unroll
            for (int off = 32; off > 0; off >>= 1) {
#pragma unroll
                for (int q = 0; q < 4; ++q)
                    dot[q] += __shfl_xor(dot[q], off, 64);
            }
#pragma unroll
            for (int q = 0; q < 4; ++q) {
                const int   kk  = pl[q] & 63;
                const float p   = __expf(dot[q] * INV_IN_SCALE + bz - NORM_TERM);
                const float num = (kk == 0) ? p : cz;
                acc += __logf(num / (p + cz));
            }
        }
        for (; i < cnt; ++i) {
            const int pl = __builtin_amdgcn_readfirstlane(payload[r0 + i]);
            const uint4 c = in8[(size_t)(pl >> 6) * 64 + lane];
            const unsigned int wd[4] = { c.x, c.y, c.z, c.w };
            float dot = 0.f;
#pragma unroll
            for (int d = 0; d < 4; ++d) {
                const floatx2 f0 = __builtin_amdgcn_cvt_pk_f32_fp8((int)wd[d], false);
                const floatx2 f1 = __builtin_amdgcn_cvt_pk_f32_fp8((int)wd[d], true);
                dot = fmaf(wf[d].x, f0.x, dot);
                dot = fmaf(wf[d].y, f0.y, dot);
                dot = fmaf(wf[d].z, f1.x, dot);
                dot = fmaf(wf[d].w, f1.y, dot);
            }
#pragma unroll
            for (int off = 32; off > 0; off >>= 1)
                dot += __shfl_xor(dot, off, 64);
            const int   kk  = pl & 63;
            const float p   = __expf(dot * INV_IN_SCALE + bz - NORM_TERM);
            const float num = (kk == 0) ? p : cz;
            acc += __logf(num / (p + cz));
        }
    }

    if (lane == 0)
        atomicAdd(&partial[gw & (NSLOTS - 1)], -acc * (1.0f / (float)NROWS));
}

// ---- k7: finish ------------------------------------------------------------
__global__ __launch_bounds__(64) void nce_finish(const float* __restrict__ partial,
                                                 float* __restrict__ out)
{
    const int lane = threadIdx.x;
    float v = partial[lane] + partial[lane + 64] + partial[lane + 128] + partial[lane + 192];
#pragma unroll
    for (int off = 32; off > 0; off >>= 1)
        v += __shfl_xor(v, off, 64);
    if (lane == 0) out[0] = v;
}

// ---- f32 fallback (R2 structure) if ws too small ---------------------------
__global__ __launch_bounds__(256) void nce_main_f32(
    const float* __restrict__ input,
    const int*   __restrict__ target,
    const int*   __restrict__ noise_samples,
    const float* __restrict__ noise,
    const float* __restrict__ weight,
    const float* __restrict__ bias,
    float*       __restrict__ partial)
{
    const int n    = blockIdx.x;
    const int tid  = threadIdx.x;
    const int wave = tid >> 6;
    const int lane = tid & 63;

    const float4* inrow = (const float4*)(input + (size_t)n * EDIM);
    float4 inv[4];
#pragma unroll
    for (int p = 0; p < 4; ++p)
        inv[p] = inrow[p * 64 + lane];

    const int start = wave * 13;
    const int end   = (start + 13 < KTOT) ? start + 13 : KTOT;

    float acc = 0.0f;
    int k = start;
    for (; k + 4 <= end; k += 4) {
        int idx[4];
#pragma unroll
        for (int i = 0; i < 4; ++i) {
            const int kk = k + i;
            idx[i] = (kk == 0) ? target[n] : noise_samples[n * KNOISE + kk - 1];
        }
        float bz[4], cz[4];
#pragma unroll
        for (int i = 0; i < 4; ++i) {
            bz[i] = bias[idx[i]];
            cz[i] = (float)KNOISE * noise[idx[i]];
        }
        float4 wr[4][4];
#pragma unroll
        for (int i = 0; i < 4; ++i) {
            const float4* wrow = (const float4*)(weight + (size_t)idx[i] * EDIM);
#pragma unroll
            for (int p = 0; p < 4; ++p)
                wr[i][p] = wrow[p * 64 + lane];
        }
        float dot[4] = {0.f, 0.f, 0.f, 0.f};
#pragma unroll
        for (int i = 0; i < 4; ++i) {
#pragma unroll
            for (int p = 0; p < 4; ++p) {
                dot[i] = fmaf(inv[p].x, wr[i][p].x, dot[i]);
                dot[i] = fmaf(inv[p].y, wr[i][p].y, dot[i]);
                dot[i] = fmaf(inv[p].z, wr[i][p].z, dot[i]);
                dot[i] = fmaf(inv[p].w, wr[i][p].w, dot[i]);
            }
        }
#pragma unroll
        for (int off = 32; off > 0; off >>= 1) {
#pragma unroll
            for (int i = 0; i < 4; ++i)
                dot[i] += __shfl_xor(dot[i], off, 64);
        }
#pragma unroll
        for (int i = 0; i < 4; ++i) {
            const float p   = __expf(dot[i] + bz[i] - NORM_TERM);
            const float num = (k + i == 0) ? p : cz[i];
            acc += __logf(num / (p + cz[i]));
        }
    }
    for (; k < end; ++k) {
        const int idx = (k == 0) ? target[n] : noise_samples[n * KNOISE + k - 1];
        const float bz = bias[idx];
        const float cz = (float)KNOISE * noise[idx];
        const float4* wrow = (const float4*)(weight + (size_t)idx * EDIM);
        float dot = 0.f;
#pragma unroll
        for (int p = 0; p < 4; ++p) {
            float4 w = wrow[p * 64 + lane];
            dot = fmaf(inv[p].x, w.x, dot);
            dot = fmaf(inv[p].y, w.y, dot);
            dot = fmaf(inv[p].z, w.z, dot);
            dot = fmaf(inv[p].w, w.w, dot);
        }
#pragma unroll
        for (int off = 32; off > 0; off >>= 1)
            dot += __shfl_xor(dot, off, 64);
        const float p   = __expf(dot + bz - NORM_TERM);
        const float num = (k == 0) ? p : cz;
        acc += __logf(num / (p + cz));
    }

    __shared__ float warr[4];
    if (lane == 0) warr[wave] = acc;
    __syncthreads();
    if (tid == 0) {
        const float s = warr[0] + warr[1] + warr[2] + warr[3];
        atomicAdd(&partial[n & (NSLOTS - 1)], -s * (1.0f / (float)NROWS));
    }
}

extern "C" void kernel_launch(void* const* d_in, const int* in_sizes, int n_in,
                              void* d_out, int out_size, void* d_ws, size_t ws_size,
                              hipStream_t stream) {
    const float* input         = (const float*)d_in[0];
    const int*   target        = (const int*)  d_in[1];
    const int*   noise_samples = (const int*)  d_in[2];
    const float* noise         = (const float*)d_in[3];
    const float* weight        = (const float*)d_in[4];
    const float* bias          = (const float*)d_in[5];
    float*       out           = (float*)d_out;

    char* ws = (char*)d_ws;
    float* partial = (float*)(ws + WS_PARTIAL);

    if (ws_size >= WS_NEED) {
        int*   hist    = (int*)(ws + WS_HIST);
        int*   cursor  = (int*)(ws + WS_CURSOR);
        int*   base    = (int*)(ws + WS_BASE);
        int*   bsum    = (int*)(ws + WS_BSUM);
        int*   boff    = (int*)(ws + WS_BOFF);
        int*   payload = (int*)(ws + WS_PAYLOAD);
        uint4* in8     = (uint4*)(ws + WS_IN8);

        // zero partial + hist in one async memset
        (void)hipMemsetAsync(ws, 0, WS_CURSOR, stream);

        convert_input_hist<<<1024, 256, 0, stream>>>(input, in8, target, noise_samples, hist);
        scan_blocksum<<<NB, 256, 0, stream>>>(hist, bsum);
        scan_offsets<<<1, 256, 0, stream>>>(bsum, boff);
        scan_final<<<NB, 256, 0, stream>>>(hist, boff, base, cursor);
        scatter_pairs<<<NPAIRS / 256, 256, 0, stream>>>(target, noise_samples, cursor, payload);

        const int waves  = (VOCAB + WR - 1) / WR;        // 12565
        const int blocks = (waves + 3) / 4;              // 3142
        nce_main_inv<<<blocks, 256, 0, stream>>>(
            in8, weight, bias, noise, base, hist, payload, partial);
    } else {
        (void)hipMemsetAsync(partial, 0, NSLOTS * sizeof(float), stream);
        nce_main_f32<<<NROWS, 256, 0, stream>>>(
            input, target, noise_samples, noise, weight, bias, partial);
    }
    nce_finish<<<1, 64, 0, stream>>>(partial, out);
}